// Round 21
// baseline (74.886 us; speedup 1.0000x reference)
//
#include <hip/hip_runtime.h>
#include <math.h>

// B=256, P=40, S=60, D=64. Round-21 = Round-20 (512-thr WG, weights + x in
// LDS, half-width GEMMs, no spill at VGPR 112) + TWO PARTS PER WAVE,
// stage-interleaved. R20 analysis: wall 69.9 us is ~3x above every pipe
// floor (MFMA 18, LDS 21, HBM 25 us) at 2 waves/SIMD -> latency-bound
// serial chain. The idle resource is the register file (112/256): running
// two independent parts per wave with every stage's (h,P) bodies adjacent
// gives the scheduler two independent dep-chains to interleave -> ~2x ILP.
// Liveness ~2x112 = 224 < 256 cap. LDS 40 KB weights + 16 x-tiles = 160 KB.
//
// Register-chain trick: MFMA contraction is invariant to permuting the k-dim.
// C/D output holds the row-dim in-lane as {16mt+4g+j}; the next GEMM
// contracting that dim takes both operands by pure register reindexing:
//     frag[nt][ks] = pk16( acc[2ks][nb], acc[2ks+1][nb] )
// map pi(ks,i,g)=16*(2ks+(i>>2))+4g+(i&3). W1/W2 pre-permuted to pi-layout.
//
// Layout facts (cdna4 guide, measured m89/m91):
//   C/D: lane holds col=lane&15, rows 16mt+4(lane>>4)+j
//   A/B: row(col)=lane&15, kappa = 32ks+8(lane>>4)+i

typedef _Float16 half8 __attribute__((ext_vector_type(8)));
typedef __fp16 fp16x2 __attribute__((ext_vector_type(2)));
typedef float f4 __attribute__((ext_vector_type(4)));

#define MFMA16(a, b, c) __builtin_amdgcn_mfma_f32_16x16x32_f16((a), (b), (c), 0, 0, 0)

__global__ __launch_bounds__(256) void prep_weights(
    const float* __restrict__ Wq, const float* __restrict__ Wk,
    const float* __restrict__ Wv, const float* __restrict__ W1,
    const float* __restrict__ W2, _Float16* __restrict__ wsH) {
    int idx = blockIdx.x * 256 + threadIdx.x;  // 0..20479
    int m = idx >> 12, r = idx & 4095;
    const float* src = (m == 0) ? Wq : (m == 1) ? Wk : (m == 2) ? Wv
                        : (m == 3) ? W1 : W2;
    float v;
    if (m < 3) {
        v = src[r];  // natural row-major [e][d]
    } else {
        // pi-permuted: position (e, kappa) holds W[e][ d=16*(2ks+(i>>2))+4g+(i&3) ]
        int e = r >> 6, kp = r & 63;
        int ks = kp >> 5, gg = (kp >> 3) & 3, i = kp & 7;
        int d = 16 * (2 * ks + (i >> 2)) + 4 * gg + (i & 3);
        v = src[e * 64 + d];
    }
    wsH[idx] = (_Float16)v;
}

// Packed f32x4 + f32x4 -> half8 via v_cvt_pkrtz_f16_f32 (4 insts).
__device__ __forceinline__ half8 pk8(f4 a, f4 b) {
    union { half8 h; fp16x2 p[4]; } u;
    u.p[0] = __builtin_amdgcn_cvt_pkrtz(a[0], a[1]);
    u.p[1] = __builtin_amdgcn_cvt_pkrtz(a[2], a[3]);
    u.p[2] = __builtin_amdgcn_cvt_pkrtz(b[0], b[1]);
    u.p[3] = __builtin_amdgcn_cvt_pkrtz(b[2], b[3]);
    return u.h;
}

// Half-width GEMM into ACC[4][2]: output cols nt in {2h, 2h+1}.
// AEXPR uses (t, ks); BEXPR uses (nt, ks); CEXPR uses (mt, nb, nt).
#define GEMM_H(ACC, AEXPR, BEXPR, CEXPR)                                     \
    do {                                                                     \
        _Pragma("unroll")                                                    \
        for (int ks = 0; ks < 2; ++ks) {                                     \
            half8 afr[4], bfr[2];                                            \
            _Pragma("unroll")                                                \
            for (int t = 0; t < 4; ++t) afr[t] = (AEXPR);                    \
            _Pragma("unroll")                                                \
            for (int nb = 0; nb < 2; ++nb) {                                 \
                const int nt = 2 * h + nb; (void)nt;                         \
                bfr[nb] = (BEXPR);                                           \
            }                                                                \
            _Pragma("unroll")                                                \
            for (int mt = 0; mt < 4; ++mt)                                   \
                _Pragma("unroll")                                            \
                for (int nb = 0; nb < 2; ++nb) {                             \
                    const int nt = 2 * h + nb; (void)nt;                     \
                    ACC[mt][nb] = MFMA16(afr[mt], bfr[nb],                   \
                                         ks == 0 ? (CEXPR) : ACC[mt][nb]);   \
                }                                                            \
        }                                                                    \
    } while (0)

// ACC -> pi-layout frags for this half (dst[2h+nb][ks]).
#define MKFR_H(dst, ACC, RELU)                                               \
    do {                                                                     \
        _Pragma("unroll")                                                    \
        for (int nb = 0; nb < 2; ++nb)                                       \
            _Pragma("unroll")                                                \
            for (int ks = 0; ks < 2; ++ks) {                                 \
                f4 a_ = ACC[2 * ks][nb], b_ = ACC[2 * ks + 1][nb];           \
                if (RELU) {                                                  \
                    _Pragma("unroll")                                        \
                    for (int j = 0; j < 4; ++j) {                            \
                        a_[j] = fmaxf(a_[j], 0.f);                           \
                        b_[j] = fmaxf(b_[j], 0.f);                           \
                    }                                                        \
                }                                                            \
                dst[2 * h + nb][ks] = pk8(a_, b_);                           \
            }                                                                \
    } while (0)

// Weight fragment from LDS: matrix widx, row-block RB (row = 16*RB+lo),
// kappa chunk (32ks+8g), XOR-swizzled by (lo&7)<<3 halves.
#define WFRAG(widx, RB) (*(const half8*)&wlds[(widx) * 4096 + (16 * (RB) + lo) * 64 + \
                                              ((32 * ks + 8 * g) ^ ((lo & 7) << 3))])

// x fragment from LDS tile at XB (rows >= 60 -> zero).
#define XFRAG(XB, RB) __extension__({                                        \
    int row_ = 16 * (RB) + lo;                                               \
    int rowc_ = row_ < 60 ? row_ : 48;                                       \
    half8 v_ = *(const half8*)&wlds[(XB) + rowc_ * 64 +                      \
                                    ((32 * ks + 8 * g) ^ ((lo & 7) << 3))];  \
    if (row_ >= 60) { half8 z_ = {}; v_ = z_; }                              \
    v_; })

__global__ __launch_bounds__(512, 1) void fused_f16(
    const float* __restrict__ x, const _Float16* __restrict__ wH,
    const float* __restrict__ bq, const float* __restrict__ bk,
    const float* __restrict__ bv, const float* __restrict__ b1,
    const float* __restrict__ b2, const float* __restrict__ W3,
    const float* __restrict__ b3, float* __restrict__ out) {
    // 40 KB weights + 16 x-tiles (60x64 f16, swizzled) = 163840 B = 160 KB.
    __shared__ __align__(16) _Float16 wlds[81920];

    const int tid = threadIdx.x;
    const int l = tid & 63;           // lane
    const int w = tid >> 6;           // wave 0..7 (TWO parts each)
    const int lo = l & 15, g = l >> 4;

    // ---- cooperative weight load global->LDS with write-side swizzle.
    #pragma unroll
    for (int rep = 0; rep < 5; ++rep) {
        int chunk = rep * 512 + tid;          // 0..2559
        int widx = chunk >> 9;
        int rem = chunk & 511;
        int row = rem >> 3, c = rem & 7;
        *(half8*)&wlds[widx * 4096 + row * 64 + ((c * 8) ^ ((row & 7) << 3))] =
            *(const half8*)&wH[widx * 4096 + row * 64 + c * 8];
    }
    __syncthreads();  // weights visible to all; waves independent afterwards

    const int pr0 = blockIdx.x * 16 + w * 2;   // two consecutive parts
    const int xb0 = 20480 + (2 * w + 0) * 3840;
    const int xb1 = 20480 + (2 * w + 1) * 3840;

    // ---- stage both parts' x into LDS (f16, swizzled); own regions.
    #pragma unroll
    for (int P = 0; P < 2; ++P) {
        const float* __restrict__ xp = x + (size_t)(pr0 + P) * (60 * 64);
        const int XB = P ? xb1 : xb0;
        #pragma unroll
        for (int m = 0; m < 8; ++m) {
            int chunk = m * 64 + l;           // 480 16B-chunks (60 rows x 8)
            if (chunk < 480) {
                int row = chunk >> 3, c = chunk & 7;
                const float* p = xp + row * 64 + c * 8;
                half8 hv = pk8(*(const f4*)p, *(const f4*)(p + 4));
                *(half8*)&wlds[XB + row * 64 + ((c * 8) ^ ((row & 7) << 3))] = hv;
            }
        }
    }

    const f4 zc = {0.f, 0.f, 0.f, 0.f};
    f4 acc2[2][4][2];                       // [P][mt][nb], static-indexed
    f4 brow[4];
    half8 qf[2][4][2], kf[2][4][2], vf[2][4][2], pf[2][4][2], wtf[2][4][2],
          h1f[2][4][2];

    // ---- qT = Wq * xT + bq  (P-interleaved)
    #pragma unroll
    for (int mt = 0; mt < 4; ++mt) brow[mt] = *(const f4*)&bq[16 * mt + 4 * g];
    #pragma unroll
    for (int h = 0; h < 2; ++h)
        #pragma unroll
        for (int P = 0; P < 2; ++P) {
            const int XB = P ? xb1 : xb0;
            GEMM_H(acc2[P], WFRAG(0, t), XFRAG(XB, nt), brow[mt]);
            MKFR_H(qf[P], acc2[P], false);
        }

    // ---- kT = Wk * xT + bk
    #pragma unroll
    for (int mt = 0; mt < 4; ++mt) brow[mt] = *(const f4*)&bk[16 * mt + 4 * g];
    #pragma unroll
    for (int h = 0; h < 2; ++h)
        #pragma unroll
        for (int P = 0; P < 2; ++P) {
            const int XB = P ? xb1 : xb0;
            GEMM_H(acc2[P], WFRAG(1, t), XFRAG(XB, nt), brow[mt]);
            MKFR_H(kf[P], acc2[P], false);
        }

    // ---- scoresT + softmax + P (both operands in regs; P-interleaved)
    #pragma unroll
    for (int h = 0; h < 2; ++h)
        #pragma unroll
        for (int P = 0; P < 2; ++P) {
            GEMM_H(acc2[P], kf[P][t][ks], qf[P][nt][ks], zc);
            #pragma unroll
            for (int nb = 0; nb < 2; ++nb) {
                float sum = 0.f;
                #pragma unroll
                for (int mt = 0; mt < 4; ++mt)
                    #pragma unroll
                    for (int j = 0; j < 4; ++j) {
                        float e = (mt == 3 && g == 3)
                                      ? 0.f
                                      : exp2f(acc2[P][mt][nb][j] *
                                              0.1803368801111137f);
                        acc2[P][mt][nb][j] = e;
                        sum += e;
                    }
                sum += __shfl_xor(sum, 16);
                sum += __shfl_xor(sum, 32);
                float inv = 1.f / sum;
                #pragma unroll
                for (int mt = 0; mt < 4; ++mt)
                    #pragma unroll
                    for (int j = 0; j < 4; ++j) acc2[P][mt][nb][j] *= inv;
            }
            MKFR_H(pf[P], acc2[P], false);
        }
    // qf, kf dead here.

    // ---- v = x * WvT + bv (col-splat C-in)
    #pragma unroll
    for (int h = 0; h < 2; ++h)
        #pragma unroll
        for (int P = 0; P < 2; ++P) {
            const int XB = P ? xb1 : xb0;
            float bc[2];
            #pragma unroll
            for (int nb = 0; nb < 2; ++nb) bc[nb] = bv[16 * (2 * h + nb) + lo];
            GEMM_H(acc2[P], XFRAG(XB, t), WFRAG(2, nt),
                   ((f4){bc[nb], bc[nb], bc[nb], bc[nb]}));
            MKFR_H(vf[P], acc2[P], false);
        }

    // ---- weightedT = vT * P (regs)
    #pragma unroll
    for (int h = 0; h < 2; ++h)
        #pragma unroll
        for (int P = 0; P < 2; ++P) {
            GEMM_H(acc2[P], vf[P][t][ks], pf[P][nt][ks], zc);
            MKFR_H(wtf[P], acc2[P], false);
        }
    // vf, pf dead here.

    // ---- h1T = relu(W1 * weightedT + b1)   (W1 pi-permuted)
    #pragma unroll
    for (int mt = 0; mt < 4; ++mt) brow[mt] = *(const f4*)&b1[16 * mt + 4 * g];
    #pragma unroll
    for (int h = 0; h < 2; ++h)
        #pragma unroll
        for (int P = 0; P < 2; ++P) {
            GEMM_H(acc2[P], WFRAG(3, t), wtf[P][nt][ks], brow[mt]);
            MKFR_H(h1f[P], acc2[P], true);
        }

    // ---- h2T = relu(W2 * h1T + b2), head folded on f32 acc
    #pragma unroll
    for (int mt = 0; mt < 4; ++mt) brow[mt] = *(const f4*)&b2[16 * mt + 4 * g];
    f4 w3r[4];
    #pragma unroll
    for (int mt = 0; mt < 4; ++mt) w3r[mt] = *(const f4*)&W3[16 * mt + 4 * g];
    float b3v = b3[0];
    #pragma unroll
    for (int h = 0; h < 2; ++h)
        #pragma unroll
        for (int P = 0; P < 2; ++P) {
            GEMM_H(acc2[P], WFRAG(4, t), h1f[P][nt][ks], brow[mt]);
            #pragma unroll
            for (int nb = 0; nb < 2; ++nb) {
                float sres = 0.f;
                #pragma unroll
                for (int mt = 0; mt < 4; ++mt)
                    #pragma unroll
                    for (int j = 0; j < 4; ++j)
                        sres += fmaxf(acc2[P][mt][nb][j], 0.f) * w3r[mt][j];
                sres += __shfl_xor(sres, 16);
                sres += __shfl_xor(sres, 32);
                if (g == 0) {
                    int s = 16 * (2 * h + nb) + lo;
                    if (s < 60) out[(size_t)(pr0 + P) * 60 + s] = sres + b3v;
                }
            }
        }
}

extern "C" void kernel_launch(void* const* d_in, const int* in_sizes, int n_in,
                              void* d_out, int out_size, void* d_ws, size_t ws_size,
                              hipStream_t stream) {
    const float* x  = (const float*)d_in[0];
    const float* Wq = (const float*)d_in[1];
    const float* bq = (const float*)d_in[2];
    const float* Wk = (const float*)d_in[3];
    const float* bk = (const float*)d_in[4];
    const float* Wv = (const float*)d_in[5];
    const float* bv = (const float*)d_in[6];
    const float* W1 = (const float*)d_in[7];
    const float* b1 = (const float*)d_in[8];
    const float* W2 = (const float*)d_in[9];
    const float* b2 = (const float*)d_in[10];
    const float* W3 = (const float*)d_in[11];
    const float* b3 = (const float*)d_in[12];
    _Float16* wsH = (_Float16*)d_ws;  // 5 * 4096 halves = 40 KB

    prep_weights<<<80, 256, 0, stream>>>(Wq, Wk, Wv, W1, W2, wsH);
    // 640 WGs x 512 thr = 8 waves/WG, TWO parts per wave (stage-interleaved);
    // weights + 16 x-tiles in LDS (160 KB); launch_bounds(512,1) -> cap 256.
    fused_f16<<<640, 512, 0, stream>>>(x, wsH, bq, bk, bv, b1, b2, W3, b3,
                                       (float*)d_out);
}